// Round 3
// baseline (1767.544 us; speedup 1.0000x reference)
//
#include <hip/hip_runtime.h>
#include <hip/hip_bf16.h>

// ---------------------------------------------------------------------------
// GCN 2-layer forward on MI355X.
// Math: out = sigmoid(Agg(relu(Agg(x@W1)+b1)@W2)+b2) with symmetric norm.
// Factorization: norm = dinv[src]*dinv[dst]  =>
//   h' = dinv[i] * (h @ W)          (fused into GEMM epilogue)
//   agg[d] = dinv[d]*(h'[d] + sum_{e:dst=d} h'[src])  (+bias, +activation)
// CSR built per call (harness re-poisons workspace every launch).
// ---------------------------------------------------------------------------

#define WAVE 64

// ---------------- degree histogram ----------------
__global__ __launch_bounds__(256) void deg_count_kernel(
    const int* __restrict__ dst, int* __restrict__ deg, int E) {
  for (int e = blockIdx.x * blockDim.x + threadIdx.x; e < E;
       e += gridDim.x * blockDim.x) {
    atomicAdd(&deg[dst[e]], 1);
  }
}

// ---------------- dinv = rsqrt(deg + 1) ----------------
__global__ __launch_bounds__(256) void dinv_kernel(
    const int* __restrict__ deg, float* __restrict__ dinv, int N) {
  int i = blockIdx.x * blockDim.x + threadIdx.x;
  if (i < N) dinv[i] = rsqrtf((float)(deg[i] + 1));
}

// ---------------- single-block exclusive scan over degrees ----------------
__global__ __launch_bounds__(1024) void scan_kernel(
    const int* __restrict__ deg, int* __restrict__ row_start,
    int* __restrict__ cursor, int n) {
  __shared__ int lds[1024];
  int t = threadIdx.x;
  int C = (n + 1023) >> 10;  // chunk per thread
  int lo = t * C;
  int hi = min(lo + C, n);
  int s = 0;
  for (int i = lo; i < hi; ++i) s += deg[i];
  lds[t] = s;
  __syncthreads();
  // Hillis-Steele inclusive scan
  for (int off = 1; off < 1024; off <<= 1) {
    int v = lds[t];
    int u = (t >= off) ? lds[t - off] : 0;
    __syncthreads();
    lds[t] = v + u;
    __syncthreads();
  }
  int base = (t == 0) ? 0 : lds[t - 1];
  for (int i = lo; i < hi; ++i) {
    row_start[i] = base;
    cursor[i] = base;
    base += deg[i];
  }
  if (t == 1023) row_start[n] = base;  // == E
}

// ---------------- scatter edges into CSR ----------------
__global__ __launch_bounds__(256) void scatter_kernel(
    const int* __restrict__ src, const int* __restrict__ dst,
    int* __restrict__ cursor, int* __restrict__ csr_src, int E) {
  for (int e = blockIdx.x * blockDim.x + threadIdx.x; e < E;
       e += gridDim.x * blockDim.x) {
    int d = dst[e];
    int p = atomicAdd(&cursor[d], 1);
    csr_src[p] = src[e];
  }
}

// ---------------- fp32 tiled GEMM with dinv row-scale epilogue -------------
// C[i][j] = dinv[i] * sum_k A[i][k] * B[k][j]
#define BM 64
#define BN 64
#define BK 32
__global__ __launch_bounds__(256) void sgemm_scale_kernel(
    const float* __restrict__ A, const float* __restrict__ B,
    const float* __restrict__ dinv, float* __restrict__ C,
    int M, int N, int K) {
  __shared__ float As[BM][BK + 4];  // pad to 36 -> 16B-aligned rows, low conflict
  __shared__ float Bs[BK][BN];
  int tid = threadIdx.x;
  int tx = tid & 15;
  int ty = tid >> 4;
  int row0 = blockIdx.x * BM;
  int col0 = blockIdx.y * BN;
  float acc[4][4] = {};

  for (int k0 = 0; k0 < K; k0 += BK) {
    // stage A tile: 64 rows x 32 k = 512 float4
#pragma unroll
    for (int l = 0; l < 2; ++l) {
      int f = tid + l * 256;
      int r = f >> 3;
      int kf = (f & 7) << 2;
      int grow = row0 + r;
      float4 v = make_float4(0.f, 0.f, 0.f, 0.f);
      if (grow < M) v = *(const float4*)&A[(size_t)grow * K + k0 + kf];
      As[r][kf + 0] = v.x;
      As[r][kf + 1] = v.y;
      As[r][kf + 2] = v.z;
      As[r][kf + 3] = v.w;
    }
    // stage B tile: 32 k x 64 cols = 512 float4
#pragma unroll
    for (int l = 0; l < 2; ++l) {
      int f = tid + l * 256;
      int r = f >> 4;
      int c = (f & 15) << 2;
      float4 v = *(const float4*)&B[(size_t)(k0 + r) * N + col0 + c];
      *(float4*)&Bs[r][c] = v;
    }
    __syncthreads();
#pragma unroll
    for (int kk = 0; kk < BK; ++kk) {
      float4 b = *(const float4*)&Bs[kk][tx << 2];
#pragma unroll
      for (int i = 0; i < 4; ++i) {
        float a = As[(ty << 2) + i][kk];
        acc[i][0] = fmaf(a, b.x, acc[i][0]);
        acc[i][1] = fmaf(a, b.y, acc[i][1]);
        acc[i][2] = fmaf(a, b.z, acc[i][2]);
        acc[i][3] = fmaf(a, b.w, acc[i][3]);
      }
    }
    __syncthreads();
  }
#pragma unroll
  for (int i = 0; i < 4; ++i) {
    int r = row0 + (ty << 2) + i;
    if (r < M) {
      float di = dinv[r];
      float4 v;
      v.x = di * acc[i][0];
      v.y = di * acc[i][1];
      v.z = di * acc[i][2];
      v.w = di * acc[i][3];
      *(float4*)&C[(size_t)r * N + col0 + (tx << 2)] = v;
    }
  }
}

// ---------------- aggregation D=256, relu ----------------
// out[i] = relu(dinv[i]*(h[i] + sum_{nbr} h[src]) + bias)
__global__ __launch_bounds__(256) void agg256_relu_kernel(
    const float* __restrict__ h, const int* __restrict__ row_start,
    const int* __restrict__ csr, const float* __restrict__ dinv,
    const float* __restrict__ bias, float* __restrict__ out) {
  int i = blockIdx.x;
  int lane = threadIdx.x & 63;
  int wid = threadIdx.x >> 6;
  const float4* h4 = (const float4*)h;
  float4 acc = make_float4(0.f, 0.f, 0.f, 0.f);
  int start = row_start[i];
  int end = row_start[i + 1];
  for (int e = start + wid; e < end; e += 4) {
    int s = csr[e];
    float4 v = h4[(size_t)s * 64 + lane];
    acc.x += v.x; acc.y += v.y; acc.z += v.z; acc.w += v.w;
  }
  if (wid == 0) {  // self loop
    float4 v = h4[(size_t)i * 64 + lane];
    acc.x += v.x; acc.y += v.y; acc.z += v.z; acc.w += v.w;
  }
  __shared__ float4 red[4][64];
  red[wid][lane] = acc;
  __syncthreads();
  if (wid == 0) {
    float4 s1 = red[1][lane], s2 = red[2][lane], s3 = red[3][lane];
    float di = dinv[i];
    float4 b = ((const float4*)bias)[lane];
    float4 r;
    r.x = fmaxf(0.f, fmaf(di, acc.x + s1.x + s2.x + s3.x, b.x));
    r.y = fmaxf(0.f, fmaf(di, acc.y + s1.y + s2.y + s3.y, b.y));
    r.z = fmaxf(0.f, fmaf(di, acc.z + s1.z + s2.z + s3.z, b.z));
    r.w = fmaxf(0.f, fmaf(di, acc.w + s1.w + s2.w + s3.w, b.w));
    ((float4*)out)[(size_t)i * 64 + lane] = r;
  }
}

// ---------------- aggregation D=128, sigmoid ----------------
__global__ __launch_bounds__(256) void agg128_sigmoid_kernel(
    const float* __restrict__ h, const int* __restrict__ row_start,
    const int* __restrict__ csr, const float* __restrict__ dinv,
    const float* __restrict__ bias, float* __restrict__ out) {
  int i = blockIdx.x;
  int lane = threadIdx.x & 63;
  int wid = threadIdx.x >> 6;
  const float2* h2 = (const float2*)h;
  float2 acc = make_float2(0.f, 0.f);
  int start = row_start[i];
  int end = row_start[i + 1];
  for (int e = start + wid; e < end; e += 4) {
    int s = csr[e];
    float2 v = h2[(size_t)s * 64 + lane];
    acc.x += v.x; acc.y += v.y;
  }
  if (wid == 0) {  // self loop
    float2 v = h2[(size_t)i * 64 + lane];
    acc.x += v.x; acc.y += v.y;
  }
  __shared__ float2 red[4][64];
  red[wid][lane] = acc;
  __syncthreads();
  if (wid == 0) {
    float2 s1 = red[1][lane], s2 = red[2][lane], s3 = red[3][lane];
    float di = dinv[i];
    float2 b = ((const float2*)bias)[lane];
    float sx = fmaf(di, acc.x + s1.x + s2.x + s3.x, b.x);
    float sy = fmaf(di, acc.y + s1.y + s2.y + s3.y, b.y);
    float2 r;
    r.x = 1.f / (1.f + expf(-sx));
    r.y = 1.f / (1.f + expf(-sy));
    ((float2*)out)[(size_t)i * 64 + lane] = r;
  }
}

// ---------------------------------------------------------------------------
extern "C" void kernel_launch(void* const* d_in, const int* in_sizes, int n_in,
                              void* d_out, int out_size, void* d_ws,
                              size_t ws_size, hipStream_t stream) {
  const float* x  = (const float*)d_in[0];
  const int*   ei = (const int*)d_in[1];   // [2][E] int32
  const float* W1 = (const float*)d_in[2];
  const float* b1 = (const float*)d_in[3];
  const float* W2 = (const float*)d_in[4];
  const float* b2 = (const float*)d_in[5];
  float* out = (float*)d_out;

  const int DIN = 256, DHID = 256, DOUT = 128;
  const int N = in_sizes[0] / DIN;      // 100000
  const int E = in_sizes[1] / 2;        // 3200000
  const int* src = ei;
  const int* dst = ei + E;

  // workspace carve-up (256B aligned)
  char* ws = (char*)d_ws;
  size_t off = 0;
  auto carve = [&](size_t bytes) {
    char* p = ws + off;
    off = (off + bytes + 255) & ~(size_t)255;
    return p;
  };
  int*   deg       = (int*)  carve((size_t)N * 4);
  float* dinv      = (float*)carve((size_t)N * 4);
  int*   row_start = (int*)  carve((size_t)(N + 1) * 4);
  int*   cursor    = (int*)  carve((size_t)N * 4);
  int*   csr_src   = (int*)  carve((size_t)E * 4);
  float* h1p       = (float*)carve((size_t)N * DHID * 4);  // reused as h2p
  float* out1      = (float*)carve((size_t)N * DHID * 4);
  float* h2p       = h1p;  // overlay: h1p dead once out1 exists
  (void)ws_size; (void)n_in; (void)out_size;

  // 1. degree histogram
  hipMemsetAsync(deg, 0, (size_t)N * 4, stream);
  deg_count_kernel<<<2048, 256, 0, stream>>>(dst, deg, E);

  // 2. dinv
  dinv_kernel<<<(N + 255) / 256, 256, 0, stream>>>(deg, dinv, N);

  // 3. CSR offsets + scatter
  scan_kernel<<<1, 1024, 0, stream>>>(deg, row_start, cursor, N);
  scatter_kernel<<<2048, 256, 0, stream>>>(src, dst, cursor, csr_src, E);

  // 4. layer 1: h1p = dinv .* (x @ W1)
  {
    dim3 grid((N + BM - 1) / BM, DHID / BN);
    sgemm_scale_kernel<<<grid, 256, 0, stream>>>(x, W1, dinv, h1p, N, DHID, DIN);
  }
  // 5. out1 = relu(dinv .* (self + neighbor sum) + b1)
  agg256_relu_kernel<<<N, 256, 0, stream>>>(h1p, row_start, csr_src, dinv, b1,
                                            out1);
  // 6. layer 2: h2p = dinv .* (out1 @ W2)
  {
    dim3 grid((N + BM - 1) / BM, DOUT / BN);
    sgemm_scale_kernel<<<grid, 256, 0, stream>>>(out1, W2, dinv, h2p, N, DOUT,
                                                 DHID);
  }
  // 7. out = sigmoid(dinv .* (self + neighbor sum) + b2)
  agg128_sigmoid_kernel<<<N, 256, 0, stream>>>(h2p, row_start, csr_src, dinv,
                                               b2, out);
}

// Round 4
// 1378.703 us; speedup vs baseline: 1.2820x; 1.2820x over previous
//
#include <hip/hip_runtime.h>
#include <hip/hip_bf16.h>

// ---------------------------------------------------------------------------
// GCN 2-layer forward, bf16 intermediates + MFMA GEMMs.
//   h1b  = bf16( dinv .* (x @ W1) )          [MFMA, fp32-staged A]
//   out1 = bf16( relu(dinv .* (self+nbr sum of h1b) + b1) )
//   h2b  = bf16( dinv .* (out1 @ W2) )       [MFMA, bf16-staged A]
//   out  = fp32( sigmoid(dinv .* (self+nbr sum of h2b) + b2) )
// CSR built per call. W pre-transposed to [N][K] bf16 so both MFMA operands
// stage k-contiguous. LDS XOR-swizzle (row&7)<<4 on write AND read (rule #21).
// ---------------------------------------------------------------------------

typedef __attribute__((ext_vector_type(8))) short short8;
typedef __attribute__((ext_vector_type(4))) float f32x4;

__device__ __forceinline__ unsigned short f2bf(float f) {
  __hip_bfloat16 h = __float2bfloat16(f);
  return *reinterpret_cast<unsigned short*>(&h);
}
__device__ __forceinline__ float bf2f(unsigned short u) {
  union { unsigned int u32; float f; } v;
  v.u32 = ((unsigned int)u) << 16;
  return v.f;
}

// ---------------- degree histogram ----------------
__global__ __launch_bounds__(256) void deg_count_kernel(
    const int* __restrict__ dst, int* __restrict__ deg, int E) {
  for (int e = blockIdx.x * blockDim.x + threadIdx.x; e < E;
       e += gridDim.x * blockDim.x) {
    atomicAdd(&deg[dst[e]], 1);
  }
}

// ---------------- dinv = rsqrt(deg + 1) ----------------
__global__ __launch_bounds__(256) void dinv_kernel(
    const int* __restrict__ deg, float* __restrict__ dinv, int N) {
  int i = blockIdx.x * blockDim.x + threadIdx.x;
  if (i < N) dinv[i] = rsqrtf((float)(deg[i] + 1));
}

// ---------------- single-block exclusive scan over degrees ----------------
__global__ __launch_bounds__(1024) void scan_kernel(
    const int* __restrict__ deg, int* __restrict__ row_start,
    int* __restrict__ cursor, int n) {
  __shared__ int lds[1024];
  int t = threadIdx.x;
  int C = (n + 1023) >> 10;
  int lo = t * C;
  int hi = min(lo + C, n);
  int s = 0;
  for (int i = lo; i < hi; ++i) s += deg[i];
  lds[t] = s;
  __syncthreads();
  for (int off = 1; off < 1024; off <<= 1) {
    int v = lds[t];
    int u = (t >= off) ? lds[t - off] : 0;
    __syncthreads();
    lds[t] = v + u;
    __syncthreads();
  }
  int base = (t == 0) ? 0 : lds[t - 1];
  for (int i = lo; i < hi; ++i) {
    row_start[i] = base;
    cursor[i] = base;
    base += deg[i];
  }
  if (t == 1023) row_start[n] = base;
}

// ---------------- scatter edges into CSR ----------------
__global__ __launch_bounds__(256) void scatter_kernel(
    const int* __restrict__ src, const int* __restrict__ dst,
    int* __restrict__ cursor, int* __restrict__ csr_src, int E) {
  for (int e = blockIdx.x * blockDim.x + threadIdx.x; e < E;
       e += gridDim.x * blockDim.x) {
    int d = dst[e];
    int p = atomicAdd(&cursor[d], 1);
    csr_src[p] = src[e];
  }
}

// ---------------- W[K][N] fp32 -> WT[N][K] bf16 ----------------
__global__ __launch_bounds__(256) void transpose_cast_kernel(
    const float* __restrict__ W, unsigned short* __restrict__ WT, int K,
    int N) {
  __shared__ float t[64][65];
  int kb = blockIdx.x * 64, nb = blockIdx.y * 64;
  int tid = threadIdx.x;
#pragma unroll
  for (int it = 0; it < 16; ++it) {
    int k = it * 4 + (tid >> 6);
    int n = tid & 63;
    t[k][n] = W[(size_t)(kb + k) * N + nb + n];
  }
  __syncthreads();
#pragma unroll
  for (int it = 0; it < 16; ++it) {
    int n = it * 4 + (tid >> 6);
    int k = tid & 63;
    WT[(size_t)(nb + n) * K + kb + k] = f2bf(t[k][n]);
  }
}

// ---------------- MFMA GEMM: C[m][n] = bf16(dinv[m] * sum_k A[m][k]*B[k][n])
// A: [M][256] (fp32 or bf16), BT: [Nw][256] bf16 (pre-transposed W).
// Tile 64x64, 4 waves each 32x32 (2x2 frags of 16x16x32), full K=256 in LDS.
template <bool AFP32>
__global__ __launch_bounds__(256) void gemm_mfma_kernel(
    const void* __restrict__ Ap, const unsigned short* __restrict__ BT,
    const float* __restrict__ dinv, unsigned short* __restrict__ C, int M,
    int Nw) {
  __shared__ unsigned short As[64 * 256];  // 32 KB, swizzled
  __shared__ unsigned short Bs[64 * 256];  // 32 KB, swizzled
  const int tid = threadIdx.x;
  const int row0 = blockIdx.x * 64;
  const int col0 = blockIdx.y * 64;

  // ---- stage A (convert fp32->bf16 in regs if needed) ----
  if (AFP32) {
    const float* A = (const float*)Ap;
#pragma unroll
    for (int it = 0; it < 16; ++it) {
      int r = it * 4 + (tid >> 6);
      int k0 = (tid & 63) * 4;  // 4 elems per thread per iter
      float4 v = make_float4(0.f, 0.f, 0.f, 0.f);
      int gr = row0 + r;
      if (gr < M) v = *(const float4*)&A[(size_t)gr * 256 + k0];
      ushort4 w;
      w.x = f2bf(v.x);
      w.y = f2bf(v.y);
      w.z = f2bf(v.z);
      w.w = f2bf(v.w);
      int byte = (r * 512 + k0 * 2) ^ ((r & 7) << 4);
      *(ushort4*)((char*)As + byte) = w;
    }
  } else {
    const unsigned short* A = (const unsigned short*)Ap;
#pragma unroll
    for (int it = 0; it < 8; ++it) {
      int r = it * 8 + (tid >> 5);
      int k0 = (tid & 31) * 8;  // 8 elems (16B) per thread per iter
      uint4 u = make_uint4(0, 0, 0, 0);
      int gr = row0 + r;
      if (gr < M) u = *(const uint4*)&A[(size_t)gr * 256 + k0];
      int byte = (r * 512 + k0 * 2) ^ ((r & 7) << 4);
      *(uint4*)((char*)As + byte) = u;
    }
  }
  // ---- stage B (bf16, always in-range: Nw multiple of 64) ----
#pragma unroll
  for (int it = 0; it < 8; ++it) {
    int n = it * 8 + (tid >> 5);
    int k0 = (tid & 31) * 8;
    uint4 u = *(const uint4*)&BT[(size_t)(col0 + n) * 256 + k0];
    int byte = (n * 512 + k0 * 2) ^ ((n & 7) << 4);
    *(uint4*)((char*)Bs + byte) = u;
  }
  __syncthreads();

  // ---- MFMA main loop ----
  const int lane = tid & 63;
  const int wid = tid >> 6;
  const int wr = wid >> 1, wc = wid & 1;
  const int lr = lane & 15, lk = lane >> 4;
  f32x4 acc[2][2] = {};
#pragma unroll
  for (int ks = 0; ks < 8; ++ks) {
    int kb2 = (ks * 32 + lk * 8) * 2;  // byte offset of this lane's k-chunk
    short8 a[2], b[2];
#pragma unroll
    for (int mr = 0; mr < 2; ++mr) {
      int row = wr * 32 + mr * 16 + lr;
      int byte = (row * 512 + kb2) ^ ((row & 7) << 4);
      a[mr] = *(const short8*)((const char*)As + byte);
    }
#pragma unroll
    for (int nc = 0; nc < 2; ++nc) {
      int n = wc * 32 + nc * 16 + lr;
      int byte = (n * 512 + kb2) ^ ((n & 7) << 4);
      b[nc] = *(const short8*)((const char*)Bs + byte);
    }
#pragma unroll
    for (int mr = 0; mr < 2; ++mr)
#pragma unroll
      for (int nc = 0; nc < 2; ++nc)
        acc[mr][nc] = __builtin_amdgcn_mfma_f32_16x16x32_bf16(
            a[mr], b[nc], acc[mr][nc], 0, 0, 0);
  }

  // ---- epilogue: D col=lane&15, row=(lane>>4)*4+q ----
#pragma unroll
  for (int mr = 0; mr < 2; ++mr) {
    int mbase = row0 + wr * 32 + mr * 16 + (lane >> 4) * 4;
#pragma unroll
    for (int q = 0; q < 4; ++q) {
      int m = mbase + q;
      if (m < M) {
        float di = dinv[m];
#pragma unroll
        for (int nc = 0; nc < 2; ++nc) {
          int n = col0 + wc * 32 + nc * 16 + (lane & 15);
          C[(size_t)m * Nw + n] = f2bf(di * acc[mr][nc][q]);
        }
      }
    }
  }
}

// ---------------- aggregation D=256 bf16 in/out, relu ----------------
__global__ __launch_bounds__(256) void agg256_relu_kernel(
    const unsigned short* __restrict__ h, const int* __restrict__ row_start,
    const int* __restrict__ csr, const float* __restrict__ dinv,
    const float* __restrict__ bias, unsigned short* __restrict__ out) {
  int i = blockIdx.x;
  int lane = threadIdx.x & 63;
  int wid = threadIdx.x >> 6;
  const ushort4* h4 = (const ushort4*)h;  // 8B units; row = 64 units
  float4 a0 = make_float4(0.f, 0.f, 0.f, 0.f);
  float4 a1 = a0;
  int start = row_start[i], end = row_start[i + 1];
  int e = start + wid;
  for (; e + 4 < end; e += 8) {  // 2x unroll for MLP
    int s0 = csr[e], s1 = csr[e + 4];
    ushort4 v0 = h4[(size_t)s0 * 64 + lane];
    ushort4 v1 = h4[(size_t)s1 * 64 + lane];
    a0.x += bf2f(v0.x); a0.y += bf2f(v0.y);
    a0.z += bf2f(v0.z); a0.w += bf2f(v0.w);
    a1.x += bf2f(v1.x); a1.y += bf2f(v1.y);
    a1.z += bf2f(v1.z); a1.w += bf2f(v1.w);
  }
  if (e < end) {
    int s0 = csr[e];
    ushort4 v0 = h4[(size_t)s0 * 64 + lane];
    a0.x += bf2f(v0.x); a0.y += bf2f(v0.y);
    a0.z += bf2f(v0.z); a0.w += bf2f(v0.w);
  }
  if (wid == 0) {  // self loop
    ushort4 v = h4[(size_t)i * 64 + lane];
    a1.x += bf2f(v.x); a1.y += bf2f(v.y);
    a1.z += bf2f(v.z); a1.w += bf2f(v.w);
  }
  float4 acc;
  acc.x = a0.x + a1.x; acc.y = a0.y + a1.y;
  acc.z = a0.z + a1.z; acc.w = a0.w + a1.w;
  __shared__ float4 red[4][64];
  red[wid][lane] = acc;
  __syncthreads();
  if (wid == 0) {
    float4 s1 = red[1][lane], s2 = red[2][lane], s3 = red[3][lane];
    float di = dinv[i];
    float4 b = ((const float4*)bias)[lane];
    ushort4 o;
    o.x = f2bf(fmaxf(0.f, fmaf(di, acc.x + s1.x + s2.x + s3.x, b.x)));
    o.y = f2bf(fmaxf(0.f, fmaf(di, acc.y + s1.y + s2.y + s3.y, b.y)));
    o.z = f2bf(fmaxf(0.f, fmaf(di, acc.z + s1.z + s2.z + s3.z, b.z)));
    o.w = f2bf(fmaxf(0.f, fmaf(di, acc.w + s1.w + s2.w + s3.w, b.w)));
    ((ushort4*)out)[(size_t)i * 64 + lane] = o;
  }
}

// ---------------- aggregation D=128 bf16 in, sigmoid, fp32 out -------------
__global__ __launch_bounds__(256) void agg128_sigmoid_kernel(
    const unsigned short* __restrict__ h, const int* __restrict__ row_start,
    const int* __restrict__ csr, const float* __restrict__ dinv,
    const float* __restrict__ bias, float* __restrict__ out) {
  int i = blockIdx.x;
  int lane = threadIdx.x & 63;
  int wid = threadIdx.x >> 6;
  const ushort2* h2 = (const ushort2*)h;  // 4B units; row = 64 units
  float2 a0 = make_float2(0.f, 0.f);
  float2 a1 = a0;
  int start = row_start[i], end = row_start[i + 1];
  int e = start + wid;
  for (; e + 4 < end; e += 8) {
    int s0 = csr[e], s1 = csr[e + 4];
    ushort2 v0 = h2[(size_t)s0 * 64 + lane];
    ushort2 v1 = h2[(size_t)s1 * 64 + lane];
    a0.x += bf2f(v0.x); a0.y += bf2f(v0.y);
    a1.x += bf2f(v1.x); a1.y += bf2f(v1.y);
  }
  if (e < end) {
    int s0 = csr[e];
    ushort2 v0 = h2[(size_t)s0 * 64 + lane];
    a0.x += bf2f(v0.x); a0.y += bf2f(v0.y);
  }
  if (wid == 0) {  // self loop
    ushort2 v = h2[(size_t)i * 64 + lane];
    a1.x += bf2f(v.x); a1.y += bf2f(v.y);
  }
  float2 acc = make_float2(a0.x + a1.x, a0.y + a1.y);
  __shared__ float2 red[4][64];
  red[wid][lane] = acc;
  __syncthreads();
  if (wid == 0) {
    float2 s1 = red[1][lane], s2 = red[2][lane], s3 = red[3][lane];
    float di = dinv[i];
    float2 b = ((const float2*)bias)[lane];
    float sx = fmaf(di, acc.x + s1.x + s2.x + s3.x, b.x);
    float sy = fmaf(di, acc.y + s1.y + s2.y + s3.y, b.y);
    float2 r;
    r.x = 1.f / (1.f + __expf(-sx));
    r.y = 1.f / (1.f + __expf(-sy));
    ((float2*)out)[(size_t)i * 64 + lane] = r;
  }
}

// ---------------------------------------------------------------------------
extern "C" void kernel_launch(void* const* d_in, const int* in_sizes, int n_in,
                              void* d_out, int out_size, void* d_ws,
                              size_t ws_size, hipStream_t stream) {
  const float* x = (const float*)d_in[0];
  const int* ei = (const int*)d_in[1];  // [2][E] int32
  const float* W1 = (const float*)d_in[2];
  const float* b1 = (const float*)d_in[3];
  const float* W2 = (const float*)d_in[4];
  const float* b2 = (const float*)d_in[5];
  float* out = (float*)d_out;

  const int DIN = 256, DHID = 256, DOUT = 128;
  const int N = in_sizes[0] / DIN;  // 100000
  const int E = in_sizes[1] / 2;    // 3200000
  const int* src = ei;
  const int* dst = ei + E;

  char* ws = (char*)d_ws;
  size_t off = 0;
  auto carve = [&](size_t bytes) {
    char* p = ws + off;
    off = (off + bytes + 255) & ~(size_t)255;
    return p;
  };
  int* deg = (int*)carve((size_t)N * 4);
  float* dinv = (float*)carve((size_t)N * 4);
  int* row_start = (int*)carve((size_t)(N + 1) * 4);
  int* cursor = (int*)carve((size_t)N * 4);
  int* csr_src = (int*)carve((size_t)E * 4);
  unsigned short* W1T = (unsigned short*)carve((size_t)DHID * DIN * 2);
  unsigned short* W2T = (unsigned short*)carve((size_t)DOUT * DHID * 2);
  unsigned short* h1b = (unsigned short*)carve((size_t)N * DHID * 2);
  unsigned short* out1b = (unsigned short*)carve((size_t)N * DHID * 2);
  unsigned short* h2b = h1b;  // overlay: h1b dead once out1b exists
  (void)ws_size; (void)n_in; (void)out_size;

  // 1. CSR + norm
  hipMemsetAsync(deg, 0, (size_t)N * 4, stream);
  deg_count_kernel<<<2048, 256, 0, stream>>>(dst, deg, E);
  dinv_kernel<<<(N + 255) / 256, 256, 0, stream>>>(deg, dinv, N);
  scan_kernel<<<1, 1024, 0, stream>>>(deg, row_start, cursor, N);
  scatter_kernel<<<2048, 256, 0, stream>>>(src, dst, cursor, csr_src, E);

  // 2. weight transpose+cast
  transpose_cast_kernel<<<dim3(DIN / 64, DHID / 64), 256, 0, stream>>>(
      W1, W1T, DIN, DHID);
  transpose_cast_kernel<<<dim3(DHID / 64, DOUT / 64), 256, 0, stream>>>(
      W2, W2T, DHID, DOUT);

  const int gM = (N + 63) / 64;
  // 3. layer 1 GEMM (A fp32), h1b = bf16(dinv .* (x @ W1))
  gemm_mfma_kernel<true><<<dim3(gM, DHID / 64), 256, 0, stream>>>(
      x, W1T, dinv, h1b, N, DHID);
  // 4. aggregation 1 -> out1b bf16
  agg256_relu_kernel<<<N, 256, 0, stream>>>(h1b, row_start, csr_src, dinv, b1,
                                            out1b);
  // 5. layer 2 GEMM (A bf16), h2b = bf16(dinv .* (out1 @ W2))
  gemm_mfma_kernel<false><<<dim3(gM, DOUT / 64), 256, 0, stream>>>(
      out1b, W2T, dinv, h2b, N, DOUT);
  // 6. aggregation 2 -> out fp32
  agg128_sigmoid_kernel<<<N, 256, 0, stream>>>(h2b, row_start, csr_src, dinv,
                                               b2, out);
}

// Round 5
// 1375.118 us; speedup vs baseline: 1.2854x; 1.0026x over previous
//
#include <hip/hip_runtime.h>
#include <hip/hip_bf16.h>

// ---------------------------------------------------------------------------
// GCN 2-layer forward, bf16 intermediates + MFMA GEMMs + binned CSR build.
//   h1b  = bf16( dinv .* (x @ W1) )          [MFMA, fp32-staged A]
//   out1 = bf16( relu(dinv .* (self+nbr sum of h1b) + b1) )
//   h2b  = bf16( dinv .* (out1 @ W2) )       [MFMA, bf16-staged A]
//   out  = fp32( sigmoid(dinv .* (self+nbr sum of h2b) + b2) )
// CSR built per call via 2-phase binned scatter (bucket = 8 dst nodes) to
// kill the 16x write amplification of direct random 4B scatter.
// ---------------------------------------------------------------------------

typedef __attribute__((ext_vector_type(8))) short short8;
typedef __attribute__((ext_vector_type(4))) float f32x4;

__device__ __forceinline__ unsigned short f2bf(float f) {
  __hip_bfloat16 h = __float2bfloat16(f);
  return *reinterpret_cast<unsigned short*>(&h);
}
__device__ __forceinline__ float bf2f(unsigned short u) {
  union { unsigned int u32; float f; } v;
  v.u32 = ((unsigned int)u) << 16;
  return v.f;
}

// ---------------- degree histogram ----------------
__global__ __launch_bounds__(256) void deg_count_kernel(
    const int* __restrict__ dst, int* __restrict__ deg, int E) {
  for (int e = blockIdx.x * blockDim.x + threadIdx.x; e < E;
       e += gridDim.x * blockDim.x) {
    atomicAdd(&deg[dst[e]], 1);
  }
}

// ---------------- dinv = rsqrt(deg + 1) ----------------
__global__ __launch_bounds__(256) void dinv_kernel(
    const int* __restrict__ deg, float* __restrict__ dinv, int N) {
  int i = blockIdx.x * blockDim.x + threadIdx.x;
  if (i < N) dinv[i] = rsqrtf((float)(deg[i] + 1));
}

// ---------------- single-block exclusive scan over degrees ----------------
__global__ __launch_bounds__(1024) void scan_kernel(
    const int* __restrict__ deg, int* __restrict__ row_start,
    int* __restrict__ cursor, int n) {
  __shared__ int lds[1024];
  int t = threadIdx.x;
  int C = (n + 1023) >> 10;
  int lo = t * C;
  int hi = min(lo + C, n);
  int s = 0;
  for (int i = lo; i < hi; ++i) s += deg[i];
  lds[t] = s;
  __syncthreads();
  for (int off = 1; off < 1024; off <<= 1) {
    int v = lds[t];
    int u = (t >= off) ? lds[t - off] : 0;
    __syncthreads();
    lds[t] = v + u;
    __syncthreads();
  }
  int base = (t == 0) ? 0 : lds[t - 1];
  for (int i = lo; i < hi; ++i) {
    row_start[i] = base;
    cursor[i] = base;
    base += deg[i];
  }
  if (t == 1023) row_start[n] = base;
}

// ---------------- bucket cursor init: bcur[b] = row_start[8b] --------------
__global__ __launch_bounds__(256) void bcur_init_kernel(
    const int* __restrict__ row_start, int* __restrict__ bcur, int NB) {
  int b = blockIdx.x * blockDim.x + threadIdx.x;
  if (b < NB) bcur[b] = row_start[b * 8];
}

// ---------------- phase A: scatter edges into bucket regions ---------------
// bucket = dst>>3; region [row_start[8b], row_start[8b+8]) is L2-hot tail.
__global__ __launch_bounds__(256) void bin_scatter_kernel(
    const int* __restrict__ src, const int* __restrict__ dst,
    int* __restrict__ bcur, unsigned* __restrict__ bedges, int E) {
  for (int e = blockIdx.x * blockDim.x + threadIdx.x; e < E;
       e += gridDim.x * blockDim.x) {
    int d = dst[e];
    int b = d >> 3;
    int p = atomicAdd(&bcur[b], 1);
    bedges[p] = ((unsigned)src[e] << 3) | (unsigned)(d & 7);
  }
}

// ---------------- phase B: bucket region -> exact per-node CSR -------------
// one wave per bucket; cursor atomics & csr writes stay in a ~1KB window.
__global__ __launch_bounds__(256) void csr_scatter_kernel(
    const unsigned* __restrict__ bedges, const int* __restrict__ row_start,
    int* __restrict__ cursor, int* __restrict__ csr_src, int N, int NB) {
  int b = blockIdx.x * 4 + (threadIdx.x >> 6);
  if (b >= NB) return;
  int lane = threadIdx.x & 63;
  int lo = row_start[b * 8];
  int hi = row_start[min(b * 8 + 8, N)];
  for (int e = lo + lane; e < hi; e += 64) {
    unsigned w = bedges[e];
    int node = b * 8 + (int)(w & 7u);
    int p = atomicAdd(&cursor[node], 1);
    csr_src[p] = (int)(w >> 3);
  }
}

// ---------------- W[K][N] fp32 -> WT[N][K] bf16 ----------------
__global__ __launch_bounds__(256) void transpose_cast_kernel(
    const float* __restrict__ W, unsigned short* __restrict__ WT, int K,
    int N) {
  __shared__ float t[64][65];
  int kb = blockIdx.x * 64, nb = blockIdx.y * 64;
  int tid = threadIdx.x;
#pragma unroll
  for (int it = 0; it < 16; ++it) {
    int k = it * 4 + (tid >> 6);
    int n = tid & 63;
    t[k][n] = W[(size_t)(kb + k) * N + nb + n];
  }
  __syncthreads();
#pragma unroll
  for (int it = 0; it < 16; ++it) {
    int n = it * 4 + (tid >> 6);
    int k = tid & 63;
    WT[(size_t)(nb + n) * K + kb + k] = f2bf(t[k][n]);
  }
}

// ---------------- MFMA GEMM: C[m][n] = bf16(dinv[m] * sum_k A[m][k]*B[k][n])
// A: [M][256] (fp32 or bf16), BT: [Nw][256] bf16 (pre-transposed W).
// Tile 64x64, 4 waves each 32x32 (2x2 frags of 16x16x32), full K=256 in LDS.
template <bool AFP32>
__global__ __launch_bounds__(256) void gemm_mfma_kernel(
    const void* __restrict__ Ap, const unsigned short* __restrict__ BT,
    const float* __restrict__ dinv, unsigned short* __restrict__ C, int M,
    int Nw) {
  __shared__ unsigned short As[64 * 256];  // 32 KB, swizzled
  __shared__ unsigned short Bs[64 * 256];  // 32 KB, swizzled
  const int tid = threadIdx.x;
  const int row0 = blockIdx.x * 64;
  const int col0 = blockIdx.y * 64;

  // ---- stage A (convert fp32->bf16 in regs if needed) ----
  if (AFP32) {
    const float* A = (const float*)Ap;
#pragma unroll
    for (int it = 0; it < 16; ++it) {
      int r = it * 4 + (tid >> 6);
      int k0 = (tid & 63) * 4;
      float4 v = make_float4(0.f, 0.f, 0.f, 0.f);
      int gr = row0 + r;
      if (gr < M) v = *(const float4*)&A[(size_t)gr * 256 + k0];
      ushort4 w;
      w.x = f2bf(v.x);
      w.y = f2bf(v.y);
      w.z = f2bf(v.z);
      w.w = f2bf(v.w);
      int byte = (r * 512 + k0 * 2) ^ ((r & 7) << 4);
      *(ushort4*)((char*)As + byte) = w;
    }
  } else {
    const unsigned short* A = (const unsigned short*)Ap;
#pragma unroll
    for (int it = 0; it < 8; ++it) {
      int r = it * 8 + (tid >> 5);
      int k0 = (tid & 31) * 8;
      uint4 u = make_uint4(0, 0, 0, 0);
      int gr = row0 + r;
      if (gr < M) u = *(const uint4*)&A[(size_t)gr * 256 + k0];
      int byte = (r * 512 + k0 * 2) ^ ((r & 7) << 4);
      *(uint4*)((char*)As + byte) = u;
    }
  }
  // ---- stage B ----
#pragma unroll
  for (int it = 0; it < 8; ++it) {
    int n = it * 8 + (tid >> 5);
    int k0 = (tid & 31) * 8;
    uint4 u = *(const uint4*)&BT[(size_t)(col0 + n) * 256 + k0];
    int byte = (n * 512 + k0 * 2) ^ ((n & 7) << 4);
    *(uint4*)((char*)Bs + byte) = u;
  }
  __syncthreads();

  // ---- MFMA main loop ----
  const int lane = tid & 63;
  const int wid = tid >> 6;
  const int wr = wid >> 1, wc = wid & 1;
  const int lr = lane & 15, lk = lane >> 4;
  f32x4 acc[2][2] = {};
#pragma unroll
  for (int ks = 0; ks < 8; ++ks) {
    int kb2 = (ks * 32 + lk * 8) * 2;
    short8 a[2], b[2];
#pragma unroll
    for (int mr = 0; mr < 2; ++mr) {
      int row = wr * 32 + mr * 16 + lr;
      int byte = (row * 512 + kb2) ^ ((row & 7) << 4);
      a[mr] = *(const short8*)((const char*)As + byte);
    }
#pragma unroll
    for (int nc = 0; nc < 2; ++nc) {
      int n = wc * 32 + nc * 16 + lr;
      int byte = (n * 512 + kb2) ^ ((n & 7) << 4);
      b[nc] = *(const short8*)((const char*)Bs + byte);
    }
#pragma unroll
    for (int mr = 0; mr < 2; ++mr)
#pragma unroll
      for (int nc = 0; nc < 2; ++nc)
        acc[mr][nc] = __builtin_amdgcn_mfma_f32_16x16x32_bf16(
            a[mr], b[nc], acc[mr][nc], 0, 0, 0);
  }

  // ---- epilogue: D col=lane&15, row=(lane>>4)*4+q ----
#pragma unroll
  for (int mr = 0; mr < 2; ++mr) {
    int mbase = row0 + wr * 32 + mr * 16 + (lane >> 4) * 4;
#pragma unroll
    for (int q = 0; q < 4; ++q) {
      int m = mbase + q;
      if (m < M) {
        float di = dinv[m];
#pragma unroll
        for (int nc = 0; nc < 2; ++nc) {
          int n = col0 + wc * 32 + nc * 16 + (lane & 15);
          C[(size_t)m * Nw + n] = f2bf(di * acc[mr][nc][q]);
        }
      }
    }
  }
}

// ---------------- aggregation D=256 bf16 in/out, relu ----------------
__global__ __launch_bounds__(256) void agg256_relu_kernel(
    const unsigned short* __restrict__ h, const int* __restrict__ row_start,
    const int* __restrict__ csr, const float* __restrict__ dinv,
    const float* __restrict__ bias, unsigned short* __restrict__ out) {
  int i = blockIdx.x;
  int lane = threadIdx.x & 63;
  int wid = threadIdx.x >> 6;
  const ushort4* h4 = (const ushort4*)h;  // 8B units; row = 64 units
  float4 a0 = make_float4(0.f, 0.f, 0.f, 0.f);
  float4 a1 = a0;
  int start = row_start[i], end = row_start[i + 1];
  int e = start + wid;
  for (; e + 4 < end; e += 8) {
    int s0 = csr[e], s1 = csr[e + 4];
    ushort4 v0 = h4[(size_t)s0 * 64 + lane];
    ushort4 v1 = h4[(size_t)s1 * 64 + lane];
    a0.x += bf2f(v0.x); a0.y += bf2f(v0.y);
    a0.z += bf2f(v0.z); a0.w += bf2f(v0.w);
    a1.x += bf2f(v1.x); a1.y += bf2f(v1.y);
    a1.z += bf2f(v1.z); a1.w += bf2f(v1.w);
  }
  if (e < end) {
    int s0 = csr[e];
    ushort4 v0 = h4[(size_t)s0 * 64 + lane];
    a0.x += bf2f(v0.x); a0.y += bf2f(v0.y);
    a0.z += bf2f(v0.z); a0.w += bf2f(v0.w);
  }
  if (wid == 0) {  // self loop
    ushort4 v = h4[(size_t)i * 64 + lane];
    a1.x += bf2f(v.x); a1.y += bf2f(v.y);
    a1.z += bf2f(v.z); a1.w += bf2f(v.w);
  }
  float4 acc;
  acc.x = a0.x + a1.x; acc.y = a0.y + a1.y;
  acc.z = a0.z + a1.z; acc.w = a0.w + a1.w;
  __shared__ float4 red[4][64];
  red[wid][lane] = acc;
  __syncthreads();
  if (wid == 0) {
    float4 s1 = red[1][lane], s2 = red[2][lane], s3 = red[3][lane];
    float di = dinv[i];
    float4 b = ((const float4*)bias)[lane];
    ushort4 o;
    o.x = f2bf(fmaxf(0.f, fmaf(di, acc.x + s1.x + s2.x + s3.x, b.x)));
    o.y = f2bf(fmaxf(0.f, fmaf(di, acc.y + s1.y + s2.y + s3.y, b.y)));
    o.z = f2bf(fmaxf(0.f, fmaf(di, acc.z + s1.z + s2.z + s3.z, b.z)));
    o.w = f2bf(fmaxf(0.f, fmaf(di, acc.w + s1.w + s2.w + s3.w, b.w)));
    ((ushort4*)out)[(size_t)i * 64 + lane] = o;
  }
}

// ---------------- aggregation D=128 bf16 in, sigmoid, fp32 out -------------
__global__ __launch_bounds__(256) void agg128_sigmoid_kernel(
    const unsigned short* __restrict__ h, const int* __restrict__ row_start,
    const int* __restrict__ csr, const float* __restrict__ dinv,
    const float* __restrict__ bias, float* __restrict__ out) {
  int i = blockIdx.x;
  int lane = threadIdx.x & 63;
  int wid = threadIdx.x >> 6;
  const ushort2* h2 = (const ushort2*)h;  // 4B units; row = 64 units
  float2 a0 = make_float2(0.f, 0.f);
  float2 a1 = a0;
  int start = row_start[i], end = row_start[i + 1];
  int e = start + wid;
  for (; e + 4 < end; e += 8) {
    int s0 = csr[e], s1 = csr[e + 4];
    ushort2 v0 = h2[(size_t)s0 * 64 + lane];
    ushort2 v1 = h2[(size_t)s1 * 64 + lane];
    a0.x += bf2f(v0.x); a0.y += bf2f(v0.y);
    a1.x += bf2f(v1.x); a1.y += bf2f(v1.y);
  }
  if (e < end) {
    int s0 = csr[e];
    ushort2 v0 = h2[(size_t)s0 * 64 + lane];
    a0.x += bf2f(v0.x); a0.y += bf2f(v0.y);
  }
  if (wid == 0) {  // self loop
    ushort2 v = h2[(size_t)i * 64 + lane];
    a1.x += bf2f(v.x); a1.y += bf2f(v.y);
  }
  float2 acc = make_float2(a0.x + a1.x, a0.y + a1.y);
  __shared__ float2 red[4][64];
  red[wid][lane] = acc;
  __syncthreads();
  if (wid == 0) {
    float2 s1 = red[1][lane], s2 = red[2][lane], s3 = red[3][lane];
    float di = dinv[i];
    float2 b = ((const float2*)bias)[lane];
    float sx = fmaf(di, acc.x + s1.x + s2.x + s3.x, b.x);
    float sy = fmaf(di, acc.y + s1.y + s2.y + s3.y, b.y);
    float2 r;
    r.x = 1.f / (1.f + __expf(-sx));
    r.y = 1.f / (1.f + __expf(-sy));
    ((float2*)out)[(size_t)i * 64 + lane] = r;
  }
}

// ---------------------------------------------------------------------------
extern "C" void kernel_launch(void* const* d_in, const int* in_sizes, int n_in,
                              void* d_out, int out_size, void* d_ws,
                              size_t ws_size, hipStream_t stream) {
  const float* x = (const float*)d_in[0];
  const int* ei = (const int*)d_in[1];  // [2][E] int32
  const float* W1 = (const float*)d_in[2];
  const float* b1 = (const float*)d_in[3];
  const float* W2 = (const float*)d_in[4];
  const float* b2 = (const float*)d_in[5];
  float* out = (float*)d_out;

  const int DIN = 256, DHID = 256, DOUT = 128;
  const int N = in_sizes[0] / DIN;  // 100000
  const int E = in_sizes[1] / 2;    // 3200000
  const int NB = (N + 7) / 8;       // buckets of 8 dst nodes
  const int* src = ei;
  const int* dst = ei + E;

  char* ws = (char*)d_ws;
  size_t off = 0;
  auto carve = [&](size_t bytes) {
    char* p = ws + off;
    off = (off + bytes + 255) & ~(size_t)255;
    return p;
  };
  int* deg = (int*)carve((size_t)N * 4);
  float* dinv = (float*)carve((size_t)N * 4);
  int* row_start = (int*)carve((size_t)(N + 1) * 4);
  int* cursor = (int*)carve((size_t)N * 4);
  int* bcur = (int*)carve((size_t)NB * 4);
  unsigned* bedges = (unsigned*)carve((size_t)E * 4);
  int* csr_src = (int*)carve((size_t)E * 4);
  unsigned short* W1T = (unsigned short*)carve((size_t)DHID * DIN * 2);
  unsigned short* W2T = (unsigned short*)carve((size_t)DOUT * DHID * 2);
  unsigned short* h1b = (unsigned short*)carve((size_t)N * DHID * 2);
  unsigned short* out1b = (unsigned short*)carve((size_t)N * DHID * 2);
  unsigned short* h2b = h1b;  // overlay: h1b dead once out1b exists
  (void)ws_size; (void)n_in; (void)out_size;

  // 1. degree + norm + offsets
  hipMemsetAsync(deg, 0, (size_t)N * 4, stream);
  deg_count_kernel<<<2048, 256, 0, stream>>>(dst, deg, E);
  dinv_kernel<<<(N + 255) / 256, 256, 0, stream>>>(deg, dinv, N);
  scan_kernel<<<1, 1024, 0, stream>>>(deg, row_start, cursor, N);

  // 2. binned CSR build (phase A: bucket scatter, phase B: node scatter)
  bcur_init_kernel<<<(NB + 255) / 256, 256, 0, stream>>>(row_start, bcur, NB);
  bin_scatter_kernel<<<2048, 256, 0, stream>>>(src, dst, bcur, bedges, E);
  csr_scatter_kernel<<<(NB + 3) / 4, 256, 0, stream>>>(bedges, row_start,
                                                       cursor, csr_src, N, NB);

  // 3. weight transpose+cast
  transpose_cast_kernel<<<dim3(DIN / 64, DHID / 64), 256, 0, stream>>>(
      W1, W1T, DIN, DHID);
  transpose_cast_kernel<<<dim3(DHID / 64, DOUT / 64), 256, 0, stream>>>(
      W2, W2T, DHID, DOUT);

  const int gM = (N + 63) / 64;
  // 4. layer 1 GEMM (A fp32), h1b = bf16(dinv .* (x @ W1))
  gemm_mfma_kernel<true><<<dim3(gM, DHID / 64), 256, 0, stream>>>(
      x, W1T, dinv, h1b, N, DHID);
  // 5. aggregation 1 -> out1b bf16
  agg256_relu_kernel<<<N, 256, 0, stream>>>(h1b, row_start, csr_src, dinv, b1,
                                            out1b);
  // 6. layer 2 GEMM (A bf16), h2b = bf16(dinv .* (out1 @ W2))
  gemm_mfma_kernel<false><<<dim3(gM, DOUT / 64), 256, 0, stream>>>(
      out1b, W2T, dinv, h2b, N, DOUT);
  // 7. aggregation 2 -> out fp32
  agg128_sigmoid_kernel<<<N, 256, 0, stream>>>(h2b, row_start, csr_src, dinv,
                                               b2, out);
}

// Round 6
// 1050.979 us; speedup vs baseline: 1.6818x; 1.3084x over previous
//
#include <hip/hip_runtime.h>
#include <hip/hip_bf16.h>

// ---------------------------------------------------------------------------
// GCN 2-layer forward, bf16 intermediates + MFMA GEMMs + binned CSR build.
//   h1b  = bf16( dinv .* (x @ W1) )          [MFMA, fp32-staged A]
//   out1 = bf16( relu(dinv .* (self+nbr sum of h1b) + b1) )
//   h2b  = bf16( dinv .* (out1 @ W2) )       [MFMA, bf16-staged A]
//   out  = fp32( sigmoid(dinv .* (self+nbr sum of h2b) + b2) )
// Round-5 changes: multi-block scan (old single-block scan was a hidden
// serial bottleneck), one-wave-per-node aggregation with 4x MLP unroll.
// ---------------------------------------------------------------------------

typedef __attribute__((ext_vector_type(8))) short short8;
typedef __attribute__((ext_vector_type(4))) float f32x4;

__device__ __forceinline__ unsigned short f2bf(float f) {
  __hip_bfloat16 h = __float2bfloat16(f);
  return *reinterpret_cast<unsigned short*>(&h);
}
__device__ __forceinline__ float bf2f(unsigned short u) {
  union { unsigned int u32; float f; } v;
  v.u32 = ((unsigned int)u) << 16;
  return v.f;
}

// ---------------- degree histogram ----------------
__global__ __launch_bounds__(256) void deg_count_kernel(
    const int* __restrict__ dst, int* __restrict__ deg, int E) {
  for (int e = blockIdx.x * blockDim.x + threadIdx.x; e < E;
       e += gridDim.x * blockDim.x) {
    atomicAdd(&deg[dst[e]], 1);
  }
}

// ---------------- dinv = rsqrt(deg + 1) ----------------
__global__ __launch_bounds__(256) void dinv_kernel(
    const int* __restrict__ deg, float* __restrict__ dinv, int N) {
  int i = blockIdx.x * blockDim.x + threadIdx.x;
  if (i < N) dinv[i] = rsqrtf((float)(deg[i] + 1));
}

// ---------------- multi-block scan, phase 1: per-block sums ----------------
__global__ __launch_bounds__(256) void scan1_kernel(
    const int* __restrict__ deg, int* __restrict__ bsum, int n) {
  int i = blockIdx.x * 256 + threadIdx.x;
  __shared__ int lds[256];
  int v = (i < n) ? deg[i] : 0;
  lds[threadIdx.x] = v;
  __syncthreads();
  // tree reduce
  for (int o = 128; o > 0; o >>= 1) {
    if (threadIdx.x < o) lds[threadIdx.x] += lds[threadIdx.x + o];
    __syncthreads();
  }
  if (threadIdx.x == 0) bsum[blockIdx.x] = lds[0];
}

// ---------------- phase 2: scan of block sums (nb <= 512) ------------------
__global__ __launch_bounds__(512) void scan2_kernel(
    const int* __restrict__ bsum, int* __restrict__ boff,
    int* __restrict__ row_start, int nb, int n) {
  __shared__ int lds[512];
  int t = threadIdx.x;
  int v = (t < nb) ? bsum[t] : 0;
  lds[t] = v;
  __syncthreads();
  for (int o = 1; o < 512; o <<= 1) {
    int x = lds[t];
    int u = (t >= o) ? lds[t - o] : 0;
    __syncthreads();
    lds[t] = x + u;
    __syncthreads();
  }
  if (t < nb) boff[t] = lds[t] - v;           // exclusive
  if (t == nb - 1) row_start[n] = lds[t];     // grand total == E
}

// ---------------- phase 3: block-local scan + offset, write outputs --------
__global__ __launch_bounds__(256) void scan3_kernel(
    const int* __restrict__ deg, const int* __restrict__ boff,
    int* __restrict__ row_start, int* __restrict__ cursor, int n) {
  int i = blockIdx.x * 256 + threadIdx.x;
  __shared__ int lds[256];
  int t = threadIdx.x;
  int v = (i < n) ? deg[i] : 0;
  lds[t] = v;
  __syncthreads();
  for (int o = 1; o < 256; o <<= 1) {
    int x = lds[t];
    int u = (t >= o) ? lds[t - o] : 0;
    __syncthreads();
    lds[t] = x + u;
    __syncthreads();
  }
  if (i < n) {
    int excl = boff[blockIdx.x] + lds[t] - v;
    row_start[i] = excl;
    cursor[i] = excl;
  }
}

// ---------------- bucket cursor init: bcur[b] = row_start[8b] --------------
__global__ __launch_bounds__(256) void bcur_init_kernel(
    const int* __restrict__ row_start, int* __restrict__ bcur, int NB) {
  int b = blockIdx.x * blockDim.x + threadIdx.x;
  if (b < NB) bcur[b] = row_start[b * 8];
}

// ---------------- phase A: scatter edges into bucket regions ---------------
__global__ __launch_bounds__(256) void bin_scatter_kernel(
    const int* __restrict__ src, const int* __restrict__ dst,
    int* __restrict__ bcur, unsigned* __restrict__ bedges, int E) {
  for (int e = blockIdx.x * blockDim.x + threadIdx.x; e < E;
       e += gridDim.x * blockDim.x) {
    int d = dst[e];
    int b = d >> 3;
    int p = atomicAdd(&bcur[b], 1);
    bedges[p] = ((unsigned)src[e] << 3) | (unsigned)(d & 7);
  }
}

// ---------------- phase B: bucket region -> exact per-node CSR -------------
__global__ __launch_bounds__(256) void csr_scatter_kernel(
    const unsigned* __restrict__ bedges, const int* __restrict__ row_start,
    int* __restrict__ cursor, int* __restrict__ csr_src, int N, int NB) {
  int b = blockIdx.x * 4 + (threadIdx.x >> 6);
  if (b >= NB) return;
  int lane = threadIdx.x & 63;
  int lo = row_start[b * 8];
  int hi = row_start[min(b * 8 + 8, N)];
  for (int e = lo + lane; e < hi; e += 64) {
    unsigned w = bedges[e];
    int node = b * 8 + (int)(w & 7u);
    int p = atomicAdd(&cursor[node], 1);
    csr_src[p] = (int)(w >> 3);
  }
}

// ---------------- W[K][N] fp32 -> WT[N][K] bf16 ----------------
__global__ __launch_bounds__(256) void transpose_cast_kernel(
    const float* __restrict__ W, unsigned short* __restrict__ WT, int K,
    int N) {
  __shared__ float t[64][65];
  int kb = blockIdx.x * 64, nb = blockIdx.y * 64;
  int tid = threadIdx.x;
#pragma unroll
  for (int it = 0; it < 16; ++it) {
    int k = it * 4 + (tid >> 6);
    int n = tid & 63;
    t[k][n] = W[(size_t)(kb + k) * N + nb + n];
  }
  __syncthreads();
#pragma unroll
  for (int it = 0; it < 16; ++it) {
    int n = it * 4 + (tid >> 6);
    int k = tid & 63;
    WT[(size_t)(nb + n) * K + kb + k] = f2bf(t[k][n]);
  }
}

// ---------------- MFMA GEMM: C[m][n] = bf16(dinv[m] * sum_k A[m][k]*B[k][n])
template <bool AFP32>
__global__ __launch_bounds__(256) void gemm_mfma_kernel(
    const void* __restrict__ Ap, const unsigned short* __restrict__ BT,
    const float* __restrict__ dinv, unsigned short* __restrict__ C, int M,
    int Nw) {
  __shared__ unsigned short As[64 * 256];  // 32 KB, swizzled
  __shared__ unsigned short Bs[64 * 256];  // 32 KB, swizzled
  const int tid = threadIdx.x;
  const int row0 = blockIdx.x * 64;
  const int col0 = blockIdx.y * 64;

  if (AFP32) {
    const float* A = (const float*)Ap;
#pragma unroll
    for (int it = 0; it < 16; ++it) {
      int r = it * 4 + (tid >> 6);
      int k0 = (tid & 63) * 4;
      float4 v = make_float4(0.f, 0.f, 0.f, 0.f);
      int gr = row0 + r;
      if (gr < M) v = *(const float4*)&A[(size_t)gr * 256 + k0];
      ushort4 w;
      w.x = f2bf(v.x);
      w.y = f2bf(v.y);
      w.z = f2bf(v.z);
      w.w = f2bf(v.w);
      int byte = (r * 512 + k0 * 2) ^ ((r & 7) << 4);
      *(ushort4*)((char*)As + byte) = w;
    }
  } else {
    const unsigned short* A = (const unsigned short*)Ap;
#pragma unroll
    for (int it = 0; it < 8; ++it) {
      int r = it * 8 + (tid >> 5);
      int k0 = (tid & 31) * 8;
      uint4 u = make_uint4(0, 0, 0, 0);
      int gr = row0 + r;
      if (gr < M) u = *(const uint4*)&A[(size_t)gr * 256 + k0];
      int byte = (r * 512 + k0 * 2) ^ ((r & 7) << 4);
      *(uint4*)((char*)As + byte) = u;
    }
  }
#pragma unroll
  for (int it = 0; it < 8; ++it) {
    int n = it * 8 + (tid >> 5);
    int k0 = (tid & 31) * 8;
    uint4 u = *(const uint4*)&BT[(size_t)(col0 + n) * 256 + k0];
    int byte = (n * 512 + k0 * 2) ^ ((n & 7) << 4);
    *(uint4*)((char*)Bs + byte) = u;
  }
  __syncthreads();

  const int lane = tid & 63;
  const int wid = tid >> 6;
  const int wr = wid >> 1, wc = wid & 1;
  const int lr = lane & 15, lk = lane >> 4;
  f32x4 acc[2][2] = {};
#pragma unroll
  for (int ks = 0; ks < 8; ++ks) {
    int kb2 = (ks * 32 + lk * 8) * 2;
    short8 a[2], b[2];
#pragma unroll
    for (int mr = 0; mr < 2; ++mr) {
      int row = wr * 32 + mr * 16 + lr;
      int byte = (row * 512 + kb2) ^ ((row & 7) << 4);
      a[mr] = *(const short8*)((const char*)As + byte);
    }
#pragma unroll
    for (int nc = 0; nc < 2; ++nc) {
      int n = wc * 32 + nc * 16 + lr;
      int byte = (n * 512 + kb2) ^ ((n & 7) << 4);
      b[nc] = *(const short8*)((const char*)Bs + byte);
    }
#pragma unroll
    for (int mr = 0; mr < 2; ++mr)
#pragma unroll
      for (int nc = 0; nc < 2; ++nc)
        acc[mr][nc] = __builtin_amdgcn_mfma_f32_16x16x32_bf16(
            a[mr], b[nc], acc[mr][nc], 0, 0, 0);
  }

#pragma unroll
  for (int mr = 0; mr < 2; ++mr) {
    int mbase = row0 + wr * 32 + mr * 16 + (lane >> 4) * 4;
#pragma unroll
    for (int q = 0; q < 4; ++q) {
      int m = mbase + q;
      if (m < M) {
        float di = dinv[m];
#pragma unroll
        for (int nc = 0; nc < 2; ++nc) {
          int n = col0 + wc * 32 + nc * 16 + (lane & 15);
          C[(size_t)m * Nw + n] = f2bf(di * acc[mr][nc][q]);
        }
      }
    }
  }
}

// ---------------- aggregation D=256 bf16 in/out, relu (1 wave/node) --------
__global__ __launch_bounds__(256) void agg256_relu_kernel(
    const unsigned short* __restrict__ h, const int* __restrict__ row_start,
    const int* __restrict__ csr, const float* __restrict__ dinv,
    const float* __restrict__ bias, unsigned short* __restrict__ out, int N) {
  int node = blockIdx.x * 4 + (threadIdx.x >> 6);
  if (node >= N) return;
  int lane = threadIdx.x & 63;
  const ushort4* h4 = (const ushort4*)h;  // 8B units; row = 64 units
  // self loop seeds accumulator 0
  ushort4 vs = h4[(size_t)node * 64 + lane];
  float4 a0, a1, a2, a3;
  a0.x = bf2f(vs.x); a0.y = bf2f(vs.y); a0.z = bf2f(vs.z); a0.w = bf2f(vs.w);
  a1 = make_float4(0.f, 0.f, 0.f, 0.f);
  a2 = a1; a3 = a1;
  int e = row_start[node], eend = row_start[node + 1];
  for (; e + 3 < eend; e += 4) {
    int i0 = csr[e], i1 = csr[e + 1], i2 = csr[e + 2], i3 = csr[e + 3];
    ushort4 v0 = h4[(size_t)i0 * 64 + lane];
    ushort4 v1 = h4[(size_t)i1 * 64 + lane];
    ushort4 v2 = h4[(size_t)i2 * 64 + lane];
    ushort4 v3 = h4[(size_t)i3 * 64 + lane];
    a0.x += bf2f(v0.x); a0.y += bf2f(v0.y);
    a0.z += bf2f(v0.z); a0.w += bf2f(v0.w);
    a1.x += bf2f(v1.x); a1.y += bf2f(v1.y);
    a1.z += bf2f(v1.z); a1.w += bf2f(v1.w);
    a2.x += bf2f(v2.x); a2.y += bf2f(v2.y);
    a2.z += bf2f(v2.z); a2.w += bf2f(v2.w);
    a3.x += bf2f(v3.x); a3.y += bf2f(v3.y);
    a3.z += bf2f(v3.z); a3.w += bf2f(v3.w);
  }
  for (; e < eend; ++e) {
    int i0 = csr[e];
    ushort4 v0 = h4[(size_t)i0 * 64 + lane];
    a0.x += bf2f(v0.x); a0.y += bf2f(v0.y);
    a0.z += bf2f(v0.z); a0.w += bf2f(v0.w);
  }
  float di = dinv[node];
  float4 b = ((const float4*)bias)[lane];
  ushort4 o;
  o.x = f2bf(fmaxf(0.f, fmaf(di, a0.x + a1.x + a2.x + a3.x, b.x)));
  o.y = f2bf(fmaxf(0.f, fmaf(di, a0.y + a1.y + a2.y + a3.y, b.y)));
  o.z = f2bf(fmaxf(0.f, fmaf(di, a0.z + a1.z + a2.z + a3.z, b.z)));
  o.w = f2bf(fmaxf(0.f, fmaf(di, a0.w + a1.w + a2.w + a3.w, b.w)));
  ((ushort4*)out)[(size_t)node * 64 + lane] = o;
}

// ---------------- aggregation D=128 bf16 in, sigmoid, fp32 out (1 wave) ----
__global__ __launch_bounds__(256) void agg128_sigmoid_kernel(
    const unsigned short* __restrict__ h, const int* __restrict__ row_start,
    const int* __restrict__ csr, const float* __restrict__ dinv,
    const float* __restrict__ bias, float* __restrict__ out, int N) {
  int node = blockIdx.x * 4 + (threadIdx.x >> 6);
  if (node >= N) return;
  int lane = threadIdx.x & 63;
  const ushort2* h2 = (const ushort2*)h;  // 4B units; row = 64 units
  ushort2 vs = h2[(size_t)node * 64 + lane];
  float2 a0 = make_float2(bf2f(vs.x), bf2f(vs.y));
  float2 a1 = make_float2(0.f, 0.f);
  float2 a2 = a1, a3 = a1;
  int e = row_start[node], eend = row_start[node + 1];
  for (; e + 3 < eend; e += 4) {
    int i0 = csr[e], i1 = csr[e + 1], i2 = csr[e + 2], i3 = csr[e + 3];
    ushort2 v0 = h2[(size_t)i0 * 64 + lane];
    ushort2 v1 = h2[(size_t)i1 * 64 + lane];
    ushort2 v2 = h2[(size_t)i2 * 64 + lane];
    ushort2 v3 = h2[(size_t)i3 * 64 + lane];
    a0.x += bf2f(v0.x); a0.y += bf2f(v0.y);
    a1.x += bf2f(v1.x); a1.y += bf2f(v1.y);
    a2.x += bf2f(v2.x); a2.y += bf2f(v2.y);
    a3.x += bf2f(v3.x); a3.y += bf2f(v3.y);
  }
  for (; e < eend; ++e) {
    int i0 = csr[e];
    ushort2 v0 = h2[(size_t)i0 * 64 + lane];
    a0.x += bf2f(v0.x); a0.y += bf2f(v0.y);
  }
  float di = dinv[node];
  float2 b = ((const float2*)bias)[lane];
  float sx = fmaf(di, a0.x + a1.x + a2.x + a3.x, b.x);
  float sy = fmaf(di, a0.y + a1.y + a2.y + a3.y, b.y);
  float2 r;
  r.x = 1.f / (1.f + __expf(-sx));
  r.y = 1.f / (1.f + __expf(-sy));
  ((float2*)out)[(size_t)node * 64 + lane] = r;
}

// ---------------------------------------------------------------------------
extern "C" void kernel_launch(void* const* d_in, const int* in_sizes, int n_in,
                              void* d_out, int out_size, void* d_ws,
                              size_t ws_size, hipStream_t stream) {
  const float* x = (const float*)d_in[0];
  const int* ei = (const int*)d_in[1];  // [2][E] int32
  const float* W1 = (const float*)d_in[2];
  const float* b1 = (const float*)d_in[3];
  const float* W2 = (const float*)d_in[4];
  const float* b2 = (const float*)d_in[5];
  float* out = (float*)d_out;

  const int DIN = 256, DHID = 256, DOUT = 128;
  const int N = in_sizes[0] / DIN;  // 100000
  const int E = in_sizes[1] / 2;    // 3200000
  const int NB = (N + 7) / 8;       // buckets of 8 dst nodes
  const int NSB = (N + 255) / 256;  // scan blocks (391 <= 512)
  const int* src = ei;
  const int* dst = ei + E;

  char* ws = (char*)d_ws;
  size_t off = 0;
  auto carve = [&](size_t bytes) {
    char* p = ws + off;
    off = (off + bytes + 255) & ~(size_t)255;
    return p;
  };
  int* deg = (int*)carve((size_t)N * 4);
  float* dinv = (float*)carve((size_t)N * 4);
  int* row_start = (int*)carve((size_t)(N + 1) * 4);
  int* cursor = (int*)carve((size_t)N * 4);
  int* bcur = (int*)carve((size_t)NB * 4);
  int* bsum = (int*)carve((size_t)NSB * 4);
  int* boff = (int*)carve((size_t)NSB * 4);
  unsigned* bedges = (unsigned*)carve((size_t)E * 4);
  int* csr_src = (int*)carve((size_t)E * 4);
  unsigned short* W1T = (unsigned short*)carve((size_t)DHID * DIN * 2);
  unsigned short* W2T = (unsigned short*)carve((size_t)DOUT * DHID * 2);
  unsigned short* h1b = (unsigned short*)carve((size_t)N * DHID * 2);
  unsigned short* out1b = (unsigned short*)carve((size_t)N * DHID * 2);
  unsigned short* h2b = h1b;  // overlay: h1b dead once out1b exists
  (void)ws_size; (void)n_in; (void)out_size;

  // 1. degree + norm + offsets (multi-block scan)
  hipMemsetAsync(deg, 0, (size_t)N * 4, stream);
  deg_count_kernel<<<2048, 256, 0, stream>>>(dst, deg, E);
  dinv_kernel<<<(N + 255) / 256, 256, 0, stream>>>(deg, dinv, N);
  scan1_kernel<<<NSB, 256, 0, stream>>>(deg, bsum, N);
  scan2_kernel<<<1, 512, 0, stream>>>(bsum, boff, row_start, NSB, N);
  scan3_kernel<<<NSB, 256, 0, stream>>>(deg, boff, row_start, cursor, N);

  // 2. binned CSR build
  bcur_init_kernel<<<(NB + 255) / 256, 256, 0, stream>>>(row_start, bcur, NB);
  bin_scatter_kernel<<<2048, 256, 0, stream>>>(src, dst, bcur, bedges, E);
  csr_scatter_kernel<<<(NB + 3) / 4, 256, 0, stream>>>(bedges, row_start,
                                                       cursor, csr_src, N, NB);

  // 3. weight transpose+cast
  transpose_cast_kernel<<<dim3(DIN / 64, DHID / 64), 256, 0, stream>>>(
      W1, W1T, DIN, DHID);
  transpose_cast_kernel<<<dim3(DHID / 64, DOUT / 64), 256, 0, stream>>>(
      W2, W2T, DHID, DOUT);

  const int gM = (N + 63) / 64;
  // 4. layer 1 GEMM (A fp32), h1b = bf16(dinv .* (x @ W1))
  gemm_mfma_kernel<true><<<dim3(gM, DHID / 64), 256, 0, stream>>>(
      x, W1T, dinv, h1b, N, DHID);
  // 5. aggregation 1 -> out1b bf16
  agg256_relu_kernel<<<(N + 3) / 4, 256, 0, stream>>>(h1b, row_start, csr_src,
                                                      dinv, b1, out1b, N);
  // 6. layer 2 GEMM (A bf16), h2b = bf16(dinv .* (out1 @ W2))
  gemm_mfma_kernel<false><<<dim3(gM, DOUT / 64), 256, 0, stream>>>(
      out1b, W2T, dinv, h2b, N, DOUT);
  // 7. aggregation 2 -> out fp32
  agg128_sigmoid_kernel<<<(N + 3) / 4, 256, 0, stream>>>(
      h2b, row_start, csr_src, dinv, b2, out, N);
}